// Round 5
// baseline (170.205 us; speedup 1.0000x reference)
//
#include <hip/hip_runtime.h>
#include <hip/hip_bf16.h>
#include <math.h>

#define NB 4
#define NT 512
#define NC 256
#define NC2 512
#define NH 4

// ---------------- K0: decode mask (robust to bool-bytes vs int32 upload) ----
__global__ void k_mask(const unsigned char* __restrict__ raw, int* __restrict__ out) {
    __shared__ int s_bytes;
    if (threadIdx.x == 0) s_bytes = 0;
    __syncthreads();
    int flag = 0;
    const unsigned* w = (const unsigned*)raw;
    for (int i = threadIdx.x; i < (NB * NT) / 4; i += blockDim.x)
        if (w[i] > 1u) flag = 1;
    if (flag) atomicOr(&s_bytes, 1);
    __syncthreads();
    const int ib = s_bytes;
    for (int i = threadIdx.x; i < NB * NT; i += blockDim.x) {
        int v = ib ? (int)raw[i] : ((const int*)raw)[i];
        out[i] = v ? 1 : 0;
    }
}

// ---------------- K1+K2 fused: pool+concat -> xnew, then projections -------
// grid 256, block 512 = 64 c4-groups x 8 kh-splits. 8 rows/block.
// Weights: b128 loads, named ping-pong prefetch (compiler can't sink).
// K-split reduced via LDS tree. L2 traffic: 1 MB/block = 256 MB total.
__global__ __launch_bounds__(512) void k_poolproj(
    const float* __restrict__ x,
    const float* __restrict__ Ws, const float* __restrict__ bs,
    const float* __restrict__ Wo, const float* __restrict__ bo,
    float* __restrict__ xnew,
    float* __restrict__ subj, float* __restrict__ obj) {
    const int r0 = blockIdx.x * 8;
    const int tid = threadIdx.x;
    __shared__ float smem[10560];                    // 42.2 KB, aliased
    float (*xraw)[260] = (float (*)[260])smem;       // [8][260]
    float (*xp)[260]   = (float (*)[260])(smem + 2080);
    float (*xt)[12]    = (float (*)[12])(smem + 4160);  // [512][12]

    // 1. stage x rows (8 x 256)
    {
        int r = tid >> 6, c4 = tid & 63;
        float4 v = *(const float4*)(x + ((size_t)(r0 + r)) * NC + c4 * 4);
        *(float4*)&xraw[r][c4 * 4] = v;
    }
    __syncthreads();
    // 2. maxpool5 along channel
#pragma unroll
    for (int p = 0; p < 4; ++p) {
        int u = p * 512 + tid;
        int r = u >> 8, c = u & 255;
        float m = xraw[r][c];
        if (c >= 1) m = fmaxf(m, xraw[r][c - 1]);
        if (c >= 2) m = fmaxf(m, xraw[r][c - 2]);
        if (c <= 254) m = fmaxf(m, xraw[r][c + 1]);
        if (c <= 253) m = fmaxf(m, xraw[r][c + 2]);
        xp[r][c] = m;
    }
    __syncthreads();
    // 3. xt transposed [k][row]; 4. xnew written coalesced
#pragma unroll
    for (int p = 0; p < 2; ++p) {
        int idx = p * 512 + tid;
        int r = idx & 7, k4 = idx >> 3;
        float4 v = (k4 < 64) ? *(const float4*)&xp[r][k4 * 4]
                             : *(const float4*)&xraw[r][(k4 - 64) * 4];
        xt[k4 * 4 + 0][r] = v.x; xt[k4 * 4 + 1][r] = v.y;
        xt[k4 * 4 + 2][r] = v.z; xt[k4 * 4 + 3][r] = v.w;
    }
#pragma unroll
    for (int p = 0; p < 2; ++p) {
        int u = p * 512 + tid;
        int r = u >> 7, k4 = u & 127;
        float4 v = (k4 < 64) ? *(const float4*)&xp[r][k4 * 4]
                             : *(const float4*)&xraw[r][(k4 - 64) * 4];
        *(float4*)(xnew + ((size_t)(r0 + r)) * NC2 + k4 * 4) = v;
    }
    __syncthreads();

    // ---- GEMM: thread = (c4: 4 cols) x (kh: 64-k slice), 8 rows in regs ----
    const int c4 = tid & 63;
    const int kh = tid >> 6;
    const int kbase = kh * 64;

    float4 as[8], ao[8];
#pragma unroll
    for (int r = 0; r < 8; ++r) {
        as[r] = make_float4(0.f, 0.f, 0.f, 0.f);
        ao[r] = make_float4(0.f, 0.f, 0.f, 0.f);
    }

    const float4* WsV = (const float4*)Ws + (size_t)kbase * 64 + c4;  // stride 64 f4 per k
    const float4* WoV = (const float4*)Wo + (size_t)kbase * 64 + c4;

    float4 wsA, woA, xaA, xbA, wsB, woB, xaB, xbB;
    wsA = WsV[0]; woA = WoV[0];
    xaA = *(const float4*)&xt[kbase][0];
    xbA = *(const float4*)&xt[kbase][4];

#define FMA8(WS, WO, XA, XB) { \
    const float xv0 = XA.x, xv1 = XA.y, xv2 = XA.z, xv3 = XA.w; \
    const float xv4 = XB.x, xv5 = XB.y, xv6 = XB.z, xv7 = XB.w; \
    as[0].x=fmaf(xv0,WS.x,as[0].x); as[0].y=fmaf(xv0,WS.y,as[0].y); as[0].z=fmaf(xv0,WS.z,as[0].z); as[0].w=fmaf(xv0,WS.w,as[0].w); \
    ao[0].x=fmaf(xv0,WO.x,ao[0].x); ao[0].y=fmaf(xv0,WO.y,ao[0].y); ao[0].z=fmaf(xv0,WO.z,ao[0].z); ao[0].w=fmaf(xv0,WO.w,ao[0].w); \
    as[1].x=fmaf(xv1,WS.x,as[1].x); as[1].y=fmaf(xv1,WS.y,as[1].y); as[1].z=fmaf(xv1,WS.z,as[1].z); as[1].w=fmaf(xv1,WS.w,as[1].w); \
    ao[1].x=fmaf(xv1,WO.x,ao[1].x); ao[1].y=fmaf(xv1,WO.y,ao[1].y); ao[1].z=fmaf(xv1,WO.z,ao[1].z); ao[1].w=fmaf(xv1,WO.w,ao[1].w); \
    as[2].x=fmaf(xv2,WS.x,as[2].x); as[2].y=fmaf(xv2,WS.y,as[2].y); as[2].z=fmaf(xv2,WS.z,as[2].z); as[2].w=fmaf(xv2,WS.w,as[2].w); \
    ao[2].x=fmaf(xv2,WO.x,ao[2].x); ao[2].y=fmaf(xv2,WO.y,ao[2].y); ao[2].z=fmaf(xv2,WO.z,ao[2].z); ao[2].w=fmaf(xv2,WO.w,ao[2].w); \
    as[3].x=fmaf(xv3,WS.x,as[3].x); as[3].y=fmaf(xv3,WS.y,as[3].y); as[3].z=fmaf(xv3,WS.z,as[3].z); as[3].w=fmaf(xv3,WS.w,as[3].w); \
    ao[3].x=fmaf(xv3,WO.x,ao[3].x); ao[3].y=fmaf(xv3,WO.y,ao[3].y); ao[3].z=fmaf(xv3,WO.z,ao[3].z); ao[3].w=fmaf(xv3,WO.w,ao[3].w); \
    as[4].x=fmaf(xv4,WS.x,as[4].x); as[4].y=fmaf(xv4,WS.y,as[4].y); as[4].z=fmaf(xv4,WS.z,as[4].z); as[4].w=fmaf(xv4,WS.w,as[4].w); \
    ao[4].x=fmaf(xv4,WO.x,ao[4].x); ao[4].y=fmaf(xv4,WO.y,ao[4].y); ao[4].z=fmaf(xv4,WO.z,ao[4].z); ao[4].w=fmaf(xv4,WO.w,ao[4].w); \
    as[5].x=fmaf(xv5,WS.x,as[5].x); as[5].y=fmaf(xv5,WS.y,as[5].y); as[5].z=fmaf(xv5,WS.z,as[5].z); as[5].w=fmaf(xv5,WS.w,as[5].w); \
    ao[5].x=fmaf(xv5,WO.x,ao[5].x); ao[5].y=fmaf(xv5,WO.y,ao[5].y); ao[5].z=fmaf(xv5,WO.z,ao[5].z); ao[5].w=fmaf(xv5,WO.w,ao[5].w); \
    as[6].x=fmaf(xv6,WS.x,as[6].x); as[6].y=fmaf(xv6,WS.y,as[6].y); as[6].z=fmaf(xv6,WS.z,as[6].z); as[6].w=fmaf(xv6,WS.w,as[6].w); \
    ao[6].x=fmaf(xv6,WO.x,ao[6].x); ao[6].y=fmaf(xv6,WO.y,ao[6].y); ao[6].z=fmaf(xv6,WO.z,ao[6].z); ao[6].w=fmaf(xv6,WO.w,ao[6].w); \
    as[7].x=fmaf(xv7,WS.x,as[7].x); as[7].y=fmaf(xv7,WS.y,as[7].y); as[7].z=fmaf(xv7,WS.z,as[7].z); as[7].w=fmaf(xv7,WS.w,as[7].w); \
    ao[7].x=fmaf(xv7,WO.x,ao[7].x); ao[7].y=fmaf(xv7,WO.y,ao[7].y); ao[7].z=fmaf(xv7,WO.z,ao[7].z); ao[7].w=fmaf(xv7,WO.w,ao[7].w); }

#define PPSTEP(K, WSC, WOC, XAC, XBC, WSN, WON, XAN, XBN) { \
    const int kn = ((K) + 1) & 63; \
    WSN = WsV[(size_t)kn * 64]; WON = WoV[(size_t)kn * 64]; \
    XAN = *(const float4*)&xt[kbase + kn][0]; \
    XBN = *(const float4*)&xt[kbase + kn][4]; \
    FMA8(WSC, WOC, XAC, XBC) }

    for (int k = 0; k < 64; k += 2) {
        PPSTEP(k,     wsA, woA, xaA, xbA, wsB, woB, xaB, xbB)
        PPSTEP(k + 1, wsB, woB, xaB, xbB, wsA, woA, xaA, xbA)
    }
#undef PPSTEP
#undef FMA8

    // ---- tree reduction over kh (8 -> 1) via LDS (aliases smem) ----
    __syncthreads();   // all xt reads done; safe to overwrite smem
    float4* rb4 = (float4*)smem;   // layout [r][slot][c4] : r*256 + slot*64 + c4
    for (int half = 4; half >= 1; half >>= 1) {
        if (kh >= half && kh < 2 * half) {
            float4* d = rb4 + (kh - half) * 64 + c4;
#pragma unroll
            for (int r = 0; r < 8; ++r) d[r * 256] = as[r];
        }
        __syncthreads();
        if (kh < half) {
            const float4* s = rb4 + kh * 64 + c4;
#pragma unroll
            for (int r = 0; r < 8; ++r) {
                float4 v = s[r * 256];
                as[r].x += v.x; as[r].y += v.y; as[r].z += v.z; as[r].w += v.w;
            }
        }
        __syncthreads();
        if (kh >= half && kh < 2 * half) {
            float4* d = rb4 + (kh - half) * 64 + c4;
#pragma unroll
            for (int r = 0; r < 8; ++r) d[r * 256] = ao[r];
        }
        __syncthreads();
        if (kh < half) {
            const float4* s = rb4 + kh * 64 + c4;
#pragma unroll
            for (int r = 0; r < 8; ++r) {
                float4 v = s[r * 256];
                ao[r].x += v.x; ao[r].y += v.y; ao[r].z += v.z; ao[r].w += v.w;
            }
        }
        __syncthreads();
    }

    if (kh == 0) {
        float4 bsv = ((const float4*)bs)[c4];
        float4 bov = ((const float4*)bo)[c4];
#pragma unroll
        for (int r = 0; r < 8; ++r) {
            float4 vs = make_float4(as[r].x + bsv.x, as[r].y + bsv.y,
                                    as[r].z + bsv.z, as[r].w + bsv.w);
            float4 vo = make_float4(ao[r].x + bov.x, ao[r].y + bov.y,
                                    ao[r].z + bov.z, ao[r].w + bov.w);
            *(float4*)&subj[(size_t)(r0 + r) * NC + c4 * 4] = vs;
            *(float4*)&obj[(size_t)(r0 + r) * NC + c4 * 4]  = vo;
        }
    }
}

// ---------------- K3: rep[b,i,j,h] = relu(sum_c |subj[j,c]-obj[i,c]| Wt[c,h] + bt[h])
// 32x64 tile, grid 512 (2 blocks/CU). Per thread 2i x 4j. Swizzled LDS.
// W_t: register ping-pong prefetch in groups of 4 rows, issued a full
// group (320 cy of FMA) ahead -> VMEM latency off the critical path.
#define OFS(r) ((r) * 68 + ((r) >> 2) * 4)
#define OFO(r) ((r) * 36 + ((r) >> 2) * 4)
__global__ __launch_bounds__(256) void k_rep(
    const float* __restrict__ subj, const float* __restrict__ obj,
    const float* __restrict__ Wt, const float* __restrict__ bt,
    float* __restrict__ attn) {
    const int bx = blockIdx.x;
    const int b = bx >> 7;
    const int rem = bx & 127;
    const int it = rem >> 3, jt = rem & 7;
    const int i0 = it * 32, j0 = jt * 64;

    __shared__ float sjT[4416];   // [c 64][j 64] swizzled
    __shared__ float obT[2368];   // [c 64][i 32] swizzled

    const int tid = threadIdx.x;
    const int tx = tid & 15;   // j = j0 + 4*tx + jj
    const int ty = tid >> 4;   // i = i0 + 2*ty + ii

    const float4* WtV = (const float4*)Wt;

    float acc[2][4][4];
#pragma unroll
    for (int ii = 0; ii < 2; ++ii)
#pragma unroll
        for (int jj = 0; jj < 4; ++jj)
#pragma unroll
            for (int h = 0; h < 4; ++h) acc[ii][jj][h] = 0.f;

#define FMABLK(Q, W4) { \
    const int cl = g4 + (Q); \
    const float4 s4 = *(const float4*)&sjT[OFS(cl) + tx * 4]; \
    const float2 o2 = *(const float2*)&obT[OFO(cl) + ty * 2]; \
    const float sv0 = s4.x, sv1 = s4.y, sv2 = s4.z, sv3 = s4.w; \
    const float ov0 = o2.x, ov1 = o2.y; \
    float d; \
    d = sv0 - ov0; \
    acc[0][0][0]=fmaf(fabsf(d),W4.x,acc[0][0][0]); acc[0][0][1]=fmaf(fabsf(d),W4.y,acc[0][0][1]); \
    acc[0][0][2]=fmaf(fabsf(d),W4.z,acc[0][0][2]); acc[0][0][3]=fmaf(fabsf(d),W4.w,acc[0][0][3]); \
    d = sv1 - ov0; \
    acc[0][1][0]=fmaf(fabsf(d),W4.x,acc[0][1][0]); acc[0][1][1]=fmaf(fabsf(d),W4.y,acc[0][1][1]); \
    acc[0][1][2]=fmaf(fabsf(d),W4.z,acc[0][1][2]); acc[0][1][3]=fmaf(fabsf(d),W4.w,acc[0][1][3]); \
    d = sv2 - ov0; \
    acc[0][2][0]=fmaf(fabsf(d),W4.x,acc[0][2][0]); acc[0][2][1]=fmaf(fabsf(d),W4.y,acc[0][2][1]); \
    acc[0][2][2]=fmaf(fabsf(d),W4.z,acc[0][2][2]); acc[0][2][3]=fmaf(fabsf(d),W4.w,acc[0][2][3]); \
    d = sv3 - ov0; \
    acc[0][3][0]=fmaf(fabsf(d),W4.x,acc[0][3][0]); acc[0][3][1]=fmaf(fabsf(d),W4.y,acc[0][3][1]); \
    acc[0][3][2]=fmaf(fabsf(d),W4.z,acc[0][3][2]); acc[0][3][3]=fmaf(fabsf(d),W4.w,acc[0][3][3]); \
    d = sv0 - ov1; \
    acc[1][0][0]=fmaf(fabsf(d),W4.x,acc[1][0][0]); acc[1][0][1]=fmaf(fabsf(d),W4.y,acc[1][0][1]); \
    acc[1][0][2]=fmaf(fabsf(d),W4.z,acc[1][0][2]); acc[1][0][3]=fmaf(fabsf(d),W4.w,acc[1][0][3]); \
    d = sv1 - ov1; \
    acc[1][1][0]=fmaf(fabsf(d),W4.x,acc[1][1][0]); acc[1][1][1]=fmaf(fabsf(d),W4.y,acc[1][1][1]); \
    acc[1][1][2]=fmaf(fabsf(d),W4.z,acc[1][1][2]); acc[1][1][3]=fmaf(fabsf(d),W4.w,acc[1][1][3]); \
    d = sv2 - ov1; \
    acc[1][2][0]=fmaf(fabsf(d),W4.x,acc[1][2][0]); acc[1][2][1]=fmaf(fabsf(d),W4.y,acc[1][2][1]); \
    acc[1][2][2]=fmaf(fabsf(d),W4.z,acc[1][2][2]); acc[1][2][3]=fmaf(fabsf(d),W4.w,acc[1][2][3]); \
    d = sv3 - ov1; \
    acc[1][3][0]=fmaf(fabsf(d),W4.x,acc[1][3][0]); acc[1][3][1]=fmaf(fabsf(d),W4.y,acc[1][3][1]); \
    acc[1][3][2]=fmaf(fabsf(d),W4.z,acc[1][3][2]); acc[1][3][3]=fmaf(fabsf(d),W4.w,acc[1][3][3]); }

#define GSTEP(G, WC0, WC1, WC2, WC3, WN0, WN1, WN2, WN3) { \
    const int gn = ((G) + 1) & 15; \
    WN0 = WtV[cc + gn * 4 + 0]; WN1 = WtV[cc + gn * 4 + 1]; \
    WN2 = WtV[cc + gn * 4 + 2]; WN3 = WtV[cc + gn * 4 + 3]; \
    const int g4 = (G) * 4; \
    FMABLK(0, WC0) FMABLK(1, WC1) FMABLK(2, WC2) FMABLK(3, WC3) }

    for (int cc = 0; cc < NC; cc += 64) {
        if (cc) __syncthreads();
        // stage subj tile (64 j x 64 c) transposed+swizzled
#pragma unroll
        for (int p = 0; p < 4; ++p) {
            int u = p * 256 + tid;
            int j = u >> 4, c4s = u & 15;
            float4 vs = *(const float4*)(subj + ((size_t)(b * NT) + j0 + j) * NC + cc + c4s * 4);
            int rb = c4s * 4;
            sjT[OFS(rb + 0) + j] = vs.x;
            sjT[OFS(rb + 1) + j] = vs.y;
            sjT[OFS(rb + 2) + j] = vs.z;
            sjT[OFS(rb + 3) + j] = vs.w;
        }
        // stage obj tile (32 i x 64 c)
#pragma unroll
        for (int p = 0; p < 2; ++p) {
            int u = p * 256 + tid;
            int i = u >> 4, c4s = u & 15;
            float4 vo = *(const float4*)(obj + ((size_t)(b * NT) + i0 + i) * NC + cc + c4s * 4);
            int rb = c4s * 4;
            obT[OFO(rb + 0) + i] = vo.x;
            obT[OFO(rb + 1) + i] = vo.y;
            obT[OFO(rb + 2) + i] = vo.z;
            obT[OFO(rb + 3) + i] = vo.w;
        }
        __syncthreads();

        float4 w0A = WtV[cc + 0], w1A = WtV[cc + 1], w2A = WtV[cc + 2], w3A = WtV[cc + 3];
        float4 w0B, w1B, w2B, w3B;
        for (int g = 0; g < 16; g += 2) {
            GSTEP(g,     w0A, w1A, w2A, w3A, w0B, w1B, w2B, w3B)
            GSTEP(g + 1, w0B, w1B, w2B, w3B, w0A, w1A, w2A, w3A)
        }
    }
#undef GSTEP
#undef FMABLK

    const float4 btv = *(const float4*)bt;
#pragma unroll
    for (int ii = 0; ii < 2; ++ii) {
        const int i = i0 + ty * 2 + ii;
#pragma unroll
        for (int jj = 0; jj < 4; ++jj) {
            const int j = j0 + tx * 4 + jj;
            float4 r;
            r.x = fmaxf(acc[ii][jj][0] + btv.x, 0.f);
            r.y = fmaxf(acc[ii][jj][1] + btv.y, 0.f);
            r.z = fmaxf(acc[ii][jj][2] + btv.z, 0.f);
            r.w = fmaxf(acc[ii][jj][3] + btv.w, 0.f);
            *(float4*)&attn[(((size_t)b * NT + i) * NT + j) * NH] = r;
        }
    }
}

// ---------------- K4: softmax over j (per b,i,h) + post-softmax mask -------
__global__ void k_soft(float* __restrict__ attn, const int* __restrict__ mask) {
    const int bi = blockIdx.x;            // b*NT + i
    const int b = bi >> 9;
    float4* row = (float4*)(attn + (size_t)bi * (NT * NH));
    const int t = threadIdx.x;
    float4 v0 = row[t];
    float4 v1 = row[t + 256];

    float mx[4] = {fmaxf(v0.x, v1.x), fmaxf(v0.y, v1.y),
                   fmaxf(v0.z, v1.z), fmaxf(v0.w, v1.w)};
#pragma unroll
    for (int off = 32; off; off >>= 1) {
#pragma unroll
        for (int h = 0; h < 4; ++h) mx[h] = fmaxf(mx[h], __shfl_xor(mx[h], off));
    }
    __shared__ float redm[4][4], reds[4][4];
    const int wid = t >> 6, lane = t & 63;
    if (lane == 0) {
#pragma unroll
        for (int h = 0; h < 4; ++h) redm[wid][h] = mx[h];
    }
    __syncthreads();
#pragma unroll
    for (int h = 0; h < 4; ++h)
        mx[h] = fmaxf(fmaxf(redm[0][h], redm[1][h]), fmaxf(redm[2][h], redm[3][h]));

    float e0[4] = {expf(v0.x - mx[0]), expf(v0.y - mx[1]),
                   expf(v0.z - mx[2]), expf(v0.w - mx[3])};
    float e1[4] = {expf(v1.x - mx[0]), expf(v1.y - mx[1]),
                   expf(v1.z - mx[2]), expf(v1.w - mx[3])};
    float sm[4] = {e0[0] + e1[0], e0[1] + e1[1], e0[2] + e1[2], e0[3] + e1[3]};
#pragma unroll
    for (int off = 32; off; off >>= 1) {
#pragma unroll
        for (int h = 0; h < 4; ++h) sm[h] += __shfl_xor(sm[h], off);
    }
    if (lane == 0) {
#pragma unroll
        for (int h = 0; h < 4; ++h) reds[wid][h] = sm[h];
    }
    __syncthreads();
    float rinv[4];
#pragma unroll
    for (int h = 0; h < 4; ++h)
        rinv[h] = 1.0f / (reds[0][h] + reds[1][h] + reds[2][h] + reds[3][h]);

    const int mi = mask[bi];
    const int mj0 = mask[b * NT + t];
    const int mj1 = mask[b * NT + t + 256];
    float4 o0, o1;
    o0.x = (mi & mj0) ? 0.f : e0[0] * rinv[0];
    o0.y = (mi & mj0) ? 0.f : e0[1] * rinv[1];
    o0.z = (mi & mj0) ? 0.f : e0[2] * rinv[2];
    o0.w = (mi & mj0) ? 0.f : e0[3] * rinv[3];
    o1.x = (mi & mj1) ? 0.f : e1[0] * rinv[0];
    o1.y = (mi & mj1) ? 0.f : e1[1] * rinv[1];
    o1.z = (mi & mj1) ? 0.f : e1[2] * rinv[2];
    o1.w = (mi & mj1) ? 0.f : e1[3] * rinv[3];
    row[t] = o0;
    row[t + 256] = o1;
}

extern "C" void kernel_launch(void* const* d_in, const int* in_sizes, int n_in,
                              void* d_out, int out_size, void* d_ws, size_t ws_size,
                              hipStream_t stream) {
    const float* x      = (const float*)d_in[0];
    const float* W_subj = (const float*)d_in[1];
    const float* b_subj = (const float*)d_in[2];
    const float* W_obj  = (const float*)d_in[3];
    const float* b_obj  = (const float*)d_in[4];
    const float* W_t    = (const float*)d_in[5];
    const float* b_t    = (const float*)d_in[6];
    const unsigned char* mask_raw = (const unsigned char*)d_in[7];

    float* xnew = (float*)d_out;                           // NB*NT*NC2 floats
    float* attn = xnew + (size_t)NB * NT * NC2;            // NB*NT*NT*NH floats

    int* wmask  = (int*)d_ws;                              // NB*NT ints
    float* subj = (float*)d_ws + NB * NT;                  // NB*NT*NC
    float* obj  = subj + (size_t)NB * NT * NC;             // NB*NT*NC

    hipLaunchKernelGGL(k_mask, dim3(1), dim3(256), 0, stream, mask_raw, wmask);
    hipLaunchKernelGGL(k_poolproj, dim3(NB * NT / 8), dim3(512), 0, stream,
                       x, W_subj, b_subj, W_obj, b_obj, xnew, subj, obj);
    hipLaunchKernelGGL(k_rep, dim3(NB * 16 * 8), dim3(256), 0, stream,
                       subj, obj, W_t, b_t, attn);
    hipLaunchKernelGGL(k_soft, dim3(NB * NT), dim3(256), 0, stream, attn, wmask);
}

// Round 8
// 140.537 us; speedup vs baseline: 1.2111x; 1.2111x over previous
//
#include <hip/hip_runtime.h>
#include <hip/hip_bf16.h>
#include <math.h>

#define NB 4
#define NT 512
#define NC 256
#define NC2 512
#define NH 4

typedef __attribute__((ext_vector_type(8))) short bf16x8;
typedef __attribute__((ext_vector_type(4))) float f32x4;

__device__ inline unsigned short f2bf(float f) {
    unsigned u = __float_as_uint(f);
    unsigned r = (u + 0x7fffu + ((u >> 16) & 1u)) >> 16;
    return (unsigned short)r;
}

// ---------------- K0: decode mask (robust to bool-bytes vs int32 upload) ----
__global__ void k_mask(const unsigned char* __restrict__ raw, int* __restrict__ out) {
    __shared__ int s_bytes;
    if (threadIdx.x == 0) s_bytes = 0;
    __syncthreads();
    int flag = 0;
    const unsigned* w = (const unsigned*)raw;
    for (int i = threadIdx.x; i < (NB * NT) / 4; i += blockDim.x)
        if (w[i] > 1u) flag = 1;
    if (flag) atomicOr(&s_bytes, 1);
    __syncthreads();
    const int ib = s_bytes;
    for (int i = threadIdx.x; i < NB * NT; i += blockDim.x) {
        int v = ib ? (int)raw[i] : ((const int*)raw)[i];
        out[i] = v ? 1 : 0;
    }
}

// ---------------- K1: pool+concat -> xnew (fp32) and xb (bf16) -------------
__global__ void k_pool(const float* __restrict__ x, float* __restrict__ xnew,
                       unsigned short* __restrict__ xb) {
    const int row = blockIdx.x;          // b*NT + t
    const int c = threadIdx.x;           // 0..255
    __shared__ float r[NC];
    r[c] = x[(size_t)row * NC + c];
    __syncthreads();
    float m = r[c];
    if (c >= 1) m = fmaxf(m, r[c - 1]);
    if (c >= 2) m = fmaxf(m, r[c - 2]);
    if (c <= 254) m = fmaxf(m, r[c + 1]);
    if (c <= 253) m = fmaxf(m, r[c + 2]);
    float* o = xnew + (size_t)row * NC2;
    o[c] = m;
    o[NC + c] = r[c];
    unsigned short* ob = xb + (size_t)row * NC2;
    ob[c] = f2bf(m);
    ob[NC + c] = f2bf(r[c]);
}

// ---------------- K2a: cast W_subj|W_obj (512x256 each) to bf16 TRANSPOSED -
// wbt[n][k], n<256 from W_subj col n, n>=256 from W_obj col n-256.
__global__ void k_wcast(const float* __restrict__ Ws, const float* __restrict__ Wo,
                        unsigned short* __restrict__ wbt) {
    __shared__ float lds[32][33];
    const int kb = blockIdx.x >> 4;       // 0..15
    const int nb = blockIdx.x & 15;       // 0..15
    const int tx = threadIdx.x & 31;
    const int ty8 = threadIdx.x >> 5;     // 0..7
    const int n0 = nb * 32;
    const int k0 = kb * 32;
    const float* src = (n0 < 256) ? Ws : Wo;
    const int ncol = n0 & 255;
#pragma unroll
    for (int rr = 0; rr < 4; ++rr) {
        int kl = ty8 * 4 + rr;
        lds[kl][tx] = src[(size_t)(k0 + kl) * NC + ncol + tx];
    }
    __syncthreads();
#pragma unroll
    for (int rr = 0; rr < 4; ++rr) {
        int nl = ty8 * 4 + rr;
        wbt[(size_t)(n0 + nl) * NC2 + k0 + tx] = f2bf(lds[tx][nl]);
    }
}

// ---------------- K2b: MFMA bf16 GEMM: [2048x512] @ [512x512] -> subj|obj --
// Block 64Mx64N (4 waves 2x2, each 32x32 = 2x2 frags of 16x16x32).
// No LDS: A rows from xb, B rows from wbt (both L2-resident), b128 frags.
#define MFMA_B16(A, B, C) __builtin_amdgcn_mfma_f32_16x16x32_bf16(A, B, C, 0, 0, 0)
__global__ __launch_bounds__(256) void k_gemm(
    const unsigned short* __restrict__ xb, const unsigned short* __restrict__ wbt,
    const float* __restrict__ bs, const float* __restrict__ bo,
    float* __restrict__ subj, float* __restrict__ obj) {
    const int bx = blockIdx.x;
    const int m0 = (bx >> 3) * 64;
    const int n0 = (bx & 7) * 64;
    const int w = threadIdx.x >> 6, lane = threadIdx.x & 63;
    const int wm = m0 + (w >> 1) * 32;
    const int wn = n0 + (w & 1) * 32;
    const int r = lane & 15, kg = lane >> 4;

    const unsigned short* aB0 = xb + (size_t)(wm + r) * NC2 + kg * 8;
    const unsigned short* aB1 = aB0 + 16 * NC2;
    const unsigned short* bB0 = wbt + (size_t)(wn + r) * NC2 + kg * 8;
    const unsigned short* bB1 = bB0 + 16 * NC2;

    f32x4 acc00 = {0.f, 0.f, 0.f, 0.f}, acc01 = {0.f, 0.f, 0.f, 0.f};
    f32x4 acc10 = {0.f, 0.f, 0.f, 0.f}, acc11 = {0.f, 0.f, 0.f, 0.f};

    bf16x8 a0 = *(const bf16x8*)(aB0);
    bf16x8 a1 = *(const bf16x8*)(aB1);
    bf16x8 b0 = *(const bf16x8*)(bB0);
    bf16x8 b1 = *(const bf16x8*)(bB1);

    for (int kk = 0; kk < NC2; kk += 64) {
        bf16x8 a0n = *(const bf16x8*)(aB0 + kk + 32);
        bf16x8 a1n = *(const bf16x8*)(aB1 + kk + 32);
        bf16x8 b0n = *(const bf16x8*)(bB0 + kk + 32);
        bf16x8 b1n = *(const bf16x8*)(bB1 + kk + 32);
        acc00 = MFMA_B16(a0, b0, acc00);
        acc01 = MFMA_B16(a0, b1, acc01);
        acc10 = MFMA_B16(a1, b0, acc10);
        acc11 = MFMA_B16(a1, b1, acc11);
        if (kk + 64 < NC2) {
            a0 = *(const bf16x8*)(aB0 + kk + 64);
            a1 = *(const bf16x8*)(aB1 + kk + 64);
            b0 = *(const bf16x8*)(bB0 + kk + 64);
            b1 = *(const bf16x8*)(bB1 + kk + 64);
        }
        acc00 = MFMA_B16(a0n, b0n, acc00);
        acc01 = MFMA_B16(a0n, b1n, acc01);
        acc10 = MFMA_B16(a1n, b0n, acc10);
        acc11 = MFMA_B16(a1n, b1n, acc11);
    }

    // C/D layout: col = lane&15, row = (lane>>4)*4 + e   [m89-verified]
#define EPI(ACC, S, T) { \
    const int col = wn + (T) * 16 + r; \
    const int rowb = wm + (S) * 16 + kg * 4; \
    const float bias = (col < NC) ? bs[col] : bo[col - NC]; \
    float* outp = (col < NC) ? (subj + col) : (obj + col - NC); \
    _Pragma("unroll") \
    for (int e = 0; e < 4; ++e) outp[(size_t)(rowb + e) * NC] = ACC[e] + bias; }
    EPI(acc00, 0, 0) EPI(acc01, 0, 1) EPI(acc10, 1, 0) EPI(acc11, 1, 1)
#undef EPI
}

// ---------------- K3: rep[b,i,j,h] = relu(sum_c |subj[j,c]-obj[i,c]| Wt[c,h] + bt[h])
// 32x32 tile, grid 1024 (4 blocks/CU). Thread: 2i x 2j. Async reg staging
// (load-early / write-late), swizzled LDS, W_t staged in LDS.
#define OF32(r) ((r) * 36 + (((r) >> 2) << 2))
__global__ __launch_bounds__(256) void k_rep(
    const float* __restrict__ subj, const float* __restrict__ obj,
    const float* __restrict__ Wt, const float* __restrict__ bt,
    float* __restrict__ attn) {
    const int bx = blockIdx.x;
    const int b = bx >> 8;
    const int rem = bx & 255;
    const int it = rem >> 4, jt = rem & 15;
    const int i0 = it * 32, j0 = jt * 32;
    const int bNT = b * NT;

    __shared__ float sjT[2368];
    __shared__ float obT[2368];
    __shared__ float wt4[NC * 4];

    const int tid = threadIdx.x;
    const int tx = tid & 15;   // j = j0 + 2*tx + jj
    const int ty = tid >> 4;   // i = i0 + 2*ty + ii
    const int ja = tid >> 4;   // staging row 0..15 (and +16)
    const int c4a = tid & 15;  // staging c4 0..15

    {   // W_t 256x4 -> LDS once
        float4 wv = ((const float4*)Wt)[tid];
        *(float4*)&wt4[tid * 4] = wv;
    }

    float acc[2][2][4];
#pragma unroll
    for (int ii = 0; ii < 2; ++ii)
#pragma unroll
        for (int jj = 0; jj < 2; ++jj)
#pragma unroll
            for (int h = 0; h < 4; ++h) acc[ii][jj][h] = 0.f;

    float4 vs0, vs1, vo0, vo1;
#define LOADCH(CC) { \
    vs0 = *(const float4*)(subj + ((size_t)(bNT + j0 + ja)) * NC + (CC) + c4a * 4); \
    vs1 = *(const float4*)(subj + ((size_t)(bNT + j0 + ja + 16)) * NC + (CC) + c4a * 4); \
    vo0 = *(const float4*)(obj  + ((size_t)(bNT + i0 + ja)) * NC + (CC) + c4a * 4); \
    vo1 = *(const float4*)(obj  + ((size_t)(bNT + i0 + ja + 16)) * NC + (CC) + c4a * 4); }

    LOADCH(0)

    for (int cc = 0; cc < NC; cc += 64) {
        if (cc) __syncthreads();           // all waves done reading prev chunk
        {
            const int rb = c4a * 4;
            sjT[OF32(rb + 0) + ja] = vs0.x; sjT[OF32(rb + 1) + ja] = vs0.y;
            sjT[OF32(rb + 2) + ja] = vs0.z; sjT[OF32(rb + 3) + ja] = vs0.w;
            sjT[OF32(rb + 0) + ja + 16] = vs1.x; sjT[OF32(rb + 1) + ja + 16] = vs1.y;
            sjT[OF32(rb + 2) + ja + 16] = vs1.z; sjT[OF32(rb + 3) + ja + 16] = vs1.w;
            obT[OF32(rb + 0) + ja] = vo0.x; obT[OF32(rb + 1) + ja] = vo0.y;
            obT[OF32(rb + 2) + ja] = vo0.z; obT[OF32(rb + 3) + ja] = vo0.w;
            obT[OF32(rb + 0) + ja + 16] = vo1.x; obT[OF32(rb + 1) + ja + 16] = vo1.y;
            obT[OF32(rb + 2) + ja + 16] = vo1.z; obT[OF32(rb + 3) + ja + 16] = vo1.w;
        }
        __syncthreads();                   // chunk visible
        if (cc + 64 < NC) LOADCH(cc + 64)  // async: loads in flight over compute

#pragma unroll 8
        for (int cl = 0; cl < 64; ++cl) {
            const float2 s2 = *(const float2*)&sjT[OF32(cl) + tx * 2];
            const float2 o2 = *(const float2*)&obT[OF32(cl) + ty * 2];
            const float4 w4 = *(const float4*)&wt4[(cc + cl) * 4];
            const float sv[2] = {s2.x, s2.y};
            const float ov[2] = {o2.x, o2.y};
#pragma unroll
            for (int ii = 0; ii < 2; ++ii)
#pragma unroll
                for (int jj = 0; jj < 2; ++jj) {
                    const float d = fabsf(sv[jj] - ov[ii]);
                    acc[ii][jj][0] = fmaf(d, w4.x, acc[ii][jj][0]);
                    acc[ii][jj][1] = fmaf(d, w4.y, acc[ii][jj][1]);
                    acc[ii][jj][2] = fmaf(d, w4.z, acc[ii][jj][2]);
                    acc[ii][jj][3] = fmaf(d, w4.w, acc[ii][jj][3]);
                }
        }
    }
#undef LOADCH

    const float4 btv = *(const float4*)bt;
#pragma unroll
    for (int ii = 0; ii < 2; ++ii) {
        const int i = i0 + ty * 2 + ii;
#pragma unroll
        for (int jj = 0; jj < 2; ++jj) {
            const int j = j0 + tx * 2 + jj;
            float4 rr;
            rr.x = fmaxf(acc[ii][jj][0] + btv.x, 0.f);
            rr.y = fmaxf(acc[ii][jj][1] + btv.y, 0.f);
            rr.z = fmaxf(acc[ii][jj][2] + btv.z, 0.f);
            rr.w = fmaxf(acc[ii][jj][3] + btv.w, 0.f);
            *(float4*)&attn[(((size_t)bNT + i) * NT + j) * NH] = rr;
        }
    }
}

// ---------------- K4: softmax over j + post-softmax mask -------------------
// One wave per (b,i) row; zero barriers; 8 float4 per lane.
__global__ __launch_bounds__(256) void k_soft(float* __restrict__ attn,
                                              const int* __restrict__ mask) {
    const int wv = threadIdx.x >> 6, lane = threadIdx.x & 63;
    const int bi = blockIdx.x * 4 + wv;
    const int b = bi >> 9;
    float4* row = (float4*)(attn + (size_t)bi * (NT * NH));

    float4 v[8];
#pragma unroll
    for (int q = 0; q < 8; ++q) v[q] = row[lane + 64 * q];

    float mx[4];
#pragma unroll
    for (int h = 0; h < 4; ++h) {
        float m = ((const float*)&v[0])[h];
#pragma unroll
        for (int q = 1; q < 8; ++q) m = fmaxf(m, ((const float*)&v[q])[h]);
        mx[h] = m;
    }
#pragma unroll
    for (int off = 32; off; off >>= 1) {
#pragma unroll
        for (int h = 0; h < 4; ++h) mx[h] = fmaxf(mx[h], __shfl_xor(mx[h], off));
    }

    float sm[4] = {0.f, 0.f, 0.f, 0.f};
#pragma unroll
    for (int q = 0; q < 8; ++q) {
        float4 e;
        e.x = expf(v[q].x - mx[0]); e.y = expf(v[q].y - mx[1]);
        e.z = expf(v[q].z - mx[2]); e.w = expf(v[q].w - mx[3]);
        v[q] = e;
        sm[0] += e.x; sm[1] += e.y; sm[2] += e.z; sm[3] += e.w;
    }
#pragma unroll
    for (int off = 32; off; off >>= 1) {
#pragma unroll
        for (int h = 0; h < 4; ++h) sm[h] += __shfl_xor(sm[h], off);
    }
    float rinv[4];
#pragma unroll
    for (int h = 0; h < 4; ++h) rinv[h] = 1.0f / sm[h];

    const int mi = mask[bi];
#pragma unroll
    for (int q = 0; q < 8; ++q) {
        const int mj = mask[b * NT + lane + 64 * q];
        const bool z = (mi & mj);
        float4 o;
        o.x = z ? 0.f : v[q].x * rinv[0];
        o.y = z ? 0.f : v[q].y * rinv[1];
        o.z = z ? 0.f : v[q].z * rinv[2];
        o.w = z ? 0.f : v[q].w * rinv[3];
        row[lane + 64 * q] = o;
    }
}

extern "C" void kernel_launch(void* const* d_in, const int* in_sizes, int n_in,
                              void* d_out, int out_size, void* d_ws, size_t ws_size,
                              hipStream_t stream) {
    const float* x      = (const float*)d_in[0];
    const float* W_subj = (const float*)d_in[1];
    const float* b_subj = (const float*)d_in[2];
    const float* W_obj  = (const float*)d_in[3];
    const float* b_obj  = (const float*)d_in[4];
    const float* W_t    = (const float*)d_in[5];
    const float* b_t    = (const float*)d_in[6];
    const unsigned char* mask_raw = (const unsigned char*)d_in[7];

    float* xnew = (float*)d_out;                           // NB*NT*NC2 fp32
    float* attn = xnew + (size_t)NB * NT * NC2;            // NB*NT*NT*NH fp32

    int* wmask          = (int*)d_ws;                                  // 8 KB
    float* subj         = (float*)((char*)d_ws + 8192);                // 2 MB
    float* obj          = subj + (size_t)NB * NT * NC;                 // 2 MB
    unsigned short* xb  = (unsigned short*)(obj + (size_t)NB * NT * NC);  // 2 MB
    unsigned short* wbt = xb + (size_t)NB * NT * NC2;                  // 0.5 MB

    hipLaunchKernelGGL(k_mask, dim3(1), dim3(256), 0, stream, mask_raw, wmask);
    hipLaunchKernelGGL(k_pool, dim3(NB * NT), dim3(NC), 0, stream, x, xnew, xb);
    hipLaunchKernelGGL(k_wcast, dim3(256), dim3(256), 0, stream, W_subj, W_obj, wbt);
    hipLaunchKernelGGL(k_gemm, dim3(256), dim3(256), 0, stream,
                       xb, wbt, b_subj, b_obj, subj, obj);
    hipLaunchKernelGGL(k_rep, dim3(NB * 16 * 16), dim3(256), 0, stream,
                       subj, obj, W_t, b_t, attn);
    hipLaunchKernelGGL(k_soft, dim3(NB * NT / 4), dim3(256), 0, stream, attn, wmask);
}

// Round 9
// 137.224 us; speedup vs baseline: 1.2403x; 1.0241x over previous
//
#include <hip/hip_runtime.h>
#include <hip/hip_bf16.h>
#include <math.h>

#define NB 4
#define NT 512
#define NC 256
#define NC2 512
#define NH 4

typedef __attribute__((ext_vector_type(8))) short bf16x8;
typedef __attribute__((ext_vector_type(4))) float f32x4;
typedef __attribute__((ext_vector_type(2))) float f32x2;

__device__ inline unsigned short f2bf(float f) {
    unsigned u = __float_as_uint(f);
    unsigned r = (u + 0x7fffu + ((u >> 16) & 1u)) >> 16;
    return (unsigned short)r;
}

// ---------------- K0: decode mask (robust to bool-bytes vs int32 upload) ----
__global__ void k_mask(const unsigned char* __restrict__ raw, int* __restrict__ out) {
    __shared__ int s_bytes;
    if (threadIdx.x == 0) s_bytes = 0;
    __syncthreads();
    int flag = 0;
    const unsigned* w = (const unsigned*)raw;
    for (int i = threadIdx.x; i < (NB * NT) / 4; i += blockDim.x)
        if (w[i] > 1u) flag = 1;
    if (flag) atomicOr(&s_bytes, 1);
    __syncthreads();
    const int ib = s_bytes;
    for (int i = threadIdx.x; i < NB * NT; i += blockDim.x) {
        int v = ib ? (int)raw[i] : ((const int*)raw)[i];
        out[i] = v ? 1 : 0;
    }
}

// ---------------- K1: pool+concat -> xnew (fp32) and xb (bf16) -------------
__global__ void k_pool(const float* __restrict__ x, float* __restrict__ xnew,
                       unsigned short* __restrict__ xb) {
    const int row = blockIdx.x;          // b*NT + t
    const int c = threadIdx.x;           // 0..255
    __shared__ float r[NC];
    r[c] = x[(size_t)row * NC + c];
    __syncthreads();
    float m = r[c];
    if (c >= 1) m = fmaxf(m, r[c - 1]);
    if (c >= 2) m = fmaxf(m, r[c - 2]);
    if (c <= 254) m = fmaxf(m, r[c + 1]);
    if (c <= 253) m = fmaxf(m, r[c + 2]);
    float* o = xnew + (size_t)row * NC2;
    o[c] = m;
    o[NC + c] = r[c];
    unsigned short* ob = xb + (size_t)row * NC2;
    ob[c] = f2bf(m);
    ob[NC + c] = f2bf(r[c]);
}

// ---------------- K2a: cast W_subj|W_obj (512x256 each) to bf16 TRANSPOSED -
__global__ void k_wcast(const float* __restrict__ Ws, const float* __restrict__ Wo,
                        unsigned short* __restrict__ wbt) {
    __shared__ float lds[32][33];
    const int kb = blockIdx.x >> 4;       // 0..15
    const int nb = blockIdx.x & 15;       // 0..15
    const int tx = threadIdx.x & 31;
    const int ty8 = threadIdx.x >> 5;     // 0..7
    const int n0 = nb * 32;
    const int k0 = kb * 32;
    const float* src = (n0 < 256) ? Ws : Wo;
    const int ncol = n0 & 255;
#pragma unroll
    for (int rr = 0; rr < 4; ++rr) {
        int kl = ty8 * 4 + rr;
        lds[kl][tx] = src[(size_t)(k0 + kl) * NC + ncol + tx];
    }
    __syncthreads();
#pragma unroll
    for (int rr = 0; rr < 4; ++rr) {
        int nl = ty8 * 4 + rr;
        wbt[(size_t)(n0 + nl) * NC2 + k0 + tx] = f2bf(lds[tx][nl]);
    }
}

// ---------------- K2b: MFMA bf16 GEMM: [2048x512] @ [512x512] -> subj|obj --
#define MFMA_B16(A, B, C) __builtin_amdgcn_mfma_f32_16x16x32_bf16(A, B, C, 0, 0, 0)
__global__ __launch_bounds__(256) void k_gemm(
    const unsigned short* __restrict__ xb, const unsigned short* __restrict__ wbt,
    const float* __restrict__ bs, const float* __restrict__ bo,
    float* __restrict__ subj, float* __restrict__ obj) {
    const int bx = blockIdx.x;
    const int m0 = (bx >> 3) * 64;
    const int n0 = (bx & 7) * 64;
    const int w = threadIdx.x >> 6, lane = threadIdx.x & 63;
    const int wm = m0 + (w >> 1) * 32;
    const int wn = n0 + (w & 1) * 32;
    const int r = lane & 15, kg = lane >> 4;

    const unsigned short* aB0 = xb + (size_t)(wm + r) * NC2 + kg * 8;
    const unsigned short* aB1 = aB0 + 16 * NC2;
    const unsigned short* bB0 = wbt + (size_t)(wn + r) * NC2 + kg * 8;
    const unsigned short* bB1 = bB0 + 16 * NC2;

    f32x4 acc00 = {0.f, 0.f, 0.f, 0.f}, acc01 = {0.f, 0.f, 0.f, 0.f};
    f32x4 acc10 = {0.f, 0.f, 0.f, 0.f}, acc11 = {0.f, 0.f, 0.f, 0.f};

    bf16x8 a0 = *(const bf16x8*)(aB0);
    bf16x8 a1 = *(const bf16x8*)(aB1);
    bf16x8 b0 = *(const bf16x8*)(bB0);
    bf16x8 b1 = *(const bf16x8*)(bB1);

    for (int kk = 0; kk < NC2; kk += 64) {
        bf16x8 a0n = *(const bf16x8*)(aB0 + kk + 32);
        bf16x8 a1n = *(const bf16x8*)(aB1 + kk + 32);
        bf16x8 b0n = *(const bf16x8*)(bB0 + kk + 32);
        bf16x8 b1n = *(const bf16x8*)(bB1 + kk + 32);
        acc00 = MFMA_B16(a0, b0, acc00);
        acc01 = MFMA_B16(a0, b1, acc01);
        acc10 = MFMA_B16(a1, b0, acc10);
        acc11 = MFMA_B16(a1, b1, acc11);
        if (kk + 64 < NC2) {
            a0 = *(const bf16x8*)(aB0 + kk + 64);
            a1 = *(const bf16x8*)(aB1 + kk + 64);
            b0 = *(const bf16x8*)(bB0 + kk + 64);
            b1 = *(const bf16x8*)(bB1 + kk + 64);
        }
        acc00 = MFMA_B16(a0n, b0n, acc00);
        acc01 = MFMA_B16(a0n, b1n, acc01);
        acc10 = MFMA_B16(a1n, b0n, acc10);
        acc11 = MFMA_B16(a1n, b1n, acc11);
    }

    // C/D layout: col = lane&15, row = (lane>>4)*4 + e   [m89-verified]
#define EPI(ACC, S, T) { \
    const int col = wn + (T) * 16 + r; \
    const int rowb = wm + (S) * 16 + kg * 4; \
    const float bias = (col < NC) ? bs[col] : bo[col - NC]; \
    float* outp = (col < NC) ? (subj + col) : (obj + col - NC); \
    _Pragma("unroll") \
    for (int e = 0; e < 4; ++e) outp[(size_t)(rowb + e) * NC] = ACC[e] + bias; }
    EPI(acc00, 0, 0) EPI(acc01, 0, 1) EPI(acc10, 1, 0) EPI(acc11, 1, 1)
#undef EPI
}

// ---------------- K3: rep[b,i,j,h] = relu(sum_c |subj[j,c]-obj[i,c]| Wt[c,h] + bt[h])
// 32x32 tile, grid 1024. 4i x 4j per thread; wave = c-slice (4-way K split);
// W_t via SMEM (s_load, uniform index); packed-f32 math; LDS tree reduce.
#define OF32(r) ((r) * 36 + (((r) >> 2) << 2))
__global__ __launch_bounds__(256, 3) void k_rep(
    const float* __restrict__ subj, const float* __restrict__ obj,
    const float* __restrict__ Wt, const float* __restrict__ bt,
    float* __restrict__ attn) {
    const int bx = blockIdx.x;
    const int b = bx >> 8;
    const int rem = bx & 255;
    const int it = rem >> 4, jt = rem & 15;
    const int i0 = it * 32, j0 = jt * 32;
    const int bNT = b * NT;

    __shared__ float lds_buf[4736];      // sjT[2368] | obT[2368]; reused for reduce
    float* sjT = lds_buf;
    float* obT = lds_buf + 2368;

    const int tid = threadIdx.x;
    const int cs = __builtin_amdgcn_readfirstlane(tid >> 6);  // wave id = c-slice
    const int lane = tid & 63;
    const int tx4 = (lane & 7) * 4;      // j-quad base (local)
    const int ty4 = (lane >> 3) * 4;     // i-quad base (local)
    const int csB = cs * 16;             // slice base within 64-c chunk

    const int c4a = tid & 15;            // staging: c4 within chunk
    const int jb = tid >> 4;             // staging: row 0..15 (and +16)

    const float4* WtV = (const float4*)Wt;

    f32x2 acc[4][2][4];                  // [ii][j-pair][h], f32x2 over 2 j
#pragma unroll
    for (int ii = 0; ii < 4; ++ii)
#pragma unroll
        for (int jp = 0; jp < 2; ++jp)
#pragma unroll
            for (int h = 0; h < 4; ++h) acc[ii][jp][h] = (f32x2){0.f, 0.f};

    float4 vs0, vs1, vo0, vo1;
#define LOADCH(CC) { \
    vs0 = *(const float4*)(subj + ((size_t)(bNT + j0 + jb)) * NC + (CC) + c4a * 4); \
    vs1 = *(const float4*)(subj + ((size_t)(bNT + j0 + jb + 16)) * NC + (CC) + c4a * 4); \
    vo0 = *(const float4*)(obj  + ((size_t)(bNT + i0 + jb)) * NC + (CC) + c4a * 4); \
    vo1 = *(const float4*)(obj  + ((size_t)(bNT + i0 + jb + 16)) * NC + (CC) + c4a * 4); }

    LOADCH(0)

    for (int cc = 0; cc < 4; ++cc) {
        const int cc64 = cc * 64;
        if (cc) __syncthreads();          // all waves done reading prev chunk
        {
            const int rb = c4a * 4;
            sjT[OF32(rb + 0) + jb] = vs0.x; sjT[OF32(rb + 1) + jb] = vs0.y;
            sjT[OF32(rb + 2) + jb] = vs0.z; sjT[OF32(rb + 3) + jb] = vs0.w;
            sjT[OF32(rb + 0) + jb + 16] = vs1.x; sjT[OF32(rb + 1) + jb + 16] = vs1.y;
            sjT[OF32(rb + 2) + jb + 16] = vs1.z; sjT[OF32(rb + 3) + jb + 16] = vs1.w;
            obT[OF32(rb + 0) + jb] = vo0.x; obT[OF32(rb + 1) + jb] = vo0.y;
            obT[OF32(rb + 2) + jb] = vo0.z; obT[OF32(rb + 3) + jb] = vo0.w;
            obT[OF32(rb + 0) + jb + 16] = vo1.x; obT[OF32(rb + 1) + jb + 16] = vo1.y;
            obT[OF32(rb + 2) + jb + 16] = vo1.z; obT[OF32(rb + 3) + jb + 16] = vo1.w;
        }
        __syncthreads();                  // chunk visible
        if (cc + 1 < 4) LOADCH(cc64 + 64) // prefetch next chunk over compute

#pragma unroll 8
        for (int q = 0; q < 16; ++q) {
            const int cl = csB + q;
            const float4 sv4 = *(const float4*)&sjT[OF32(cl) + tx4];
            const float4 ov4 = *(const float4*)&obT[OF32(cl) + ty4];
            const float4 w4 = WtV[cc64 + cl];   // uniform -> s_load
            const f32x2 s01 = {sv4.x, sv4.y};
            const f32x2 s23 = {sv4.z, sv4.w};
            const f32x2 w0 = {w4.x, w4.x};
            const f32x2 w1 = {w4.y, w4.y};
            const f32x2 w2 = {w4.z, w4.z};
            const f32x2 w3 = {w4.w, w4.w};
#define IIBLK(II, OV) { \
    const f32x2 ob2 = {OV, OV}; \
    const f32x2 d01 = s01 - ob2; \
    const f32x2 d23 = s23 - ob2; \
    f32x2 a01, a23; \
    a01.x = fabsf(d01.x); a01.y = fabsf(d01.y); \
    a23.x = fabsf(d23.x); a23.y = fabsf(d23.y); \
    acc[II][0][0] = a01 * w0 + acc[II][0][0]; \
    acc[II][0][1] = a01 * w1 + acc[II][0][1]; \
    acc[II][0][2] = a01 * w2 + acc[II][0][2]; \
    acc[II][0][3] = a01 * w3 + acc[II][0][3]; \
    acc[II][1][0] = a23 * w0 + acc[II][1][0]; \
    acc[II][1][1] = a23 * w1 + acc[II][1][1]; \
    acc[II][1][2] = a23 * w2 + acc[II][1][2]; \
    acc[II][1][3] = a23 * w3 + acc[II][1][3]; }
            IIBLK(0, ov4.x) IIBLK(1, ov4.y) IIBLK(2, ov4.z) IIBLK(3, ov4.w)
#undef IIBLK
        }
    }
#undef LOADCH

    // ---- cross-wave reduction over c-slices: (1->0, 3->2), then (2->0) ----
    float* rbuf = lds_buf;
    const int lb = lane * 36;            // 36-stride: b64-aligned, spread banks
#pragma unroll
    for (int half = 0; half < 2; ++half) {
        __syncthreads();
        if (cs == 1 || cs == 3) {
            float* p = rbuf + ((cs == 1) ? 0 : 2368) + lb;
#pragma unroll
            for (int k = 0; k < 16; ++k)
                *(f32x2*)(p + k * 2) = acc[half * 2 + (k >> 3)][(k >> 2) & 1][k & 3];
        }
        __syncthreads();
        if (cs == 0 || cs == 2) {
            const float* p = rbuf + ((cs == 0) ? 0 : 2368) + lb;
#pragma unroll
            for (int k = 0; k < 16; ++k)
                acc[half * 2 + (k >> 3)][(k >> 2) & 1][k & 3] += *(const f32x2*)(p + k * 2);
        }
    }
#pragma unroll
    for (int half = 0; half < 2; ++half) {
        __syncthreads();
        if (cs == 2) {
            float* p = rbuf + lb;
#pragma unroll
            for (int k = 0; k < 16; ++k)
                *(f32x2*)(p + k * 2) = acc[half * 2 + (k >> 3)][(k >> 2) & 1][k & 3];
        }
        __syncthreads();
        if (cs == 0) {
            const float* p = rbuf + lb;
#pragma unroll
            for (int k = 0; k < 16; ++k)
                acc[half * 2 + (k >> 3)][(k >> 2) & 1][k & 3] += *(const f32x2*)(p + k * 2);
        }
    }

    if (cs == 0) {
        const float4 btv = *(const float4*)bt;
#pragma unroll
        for (int ii = 0; ii < 4; ++ii) {
            const int i = i0 + ty4 + ii;
            float* orow = attn + (((size_t)(bNT + i)) * NT + (j0 + tx4)) * NH;
            float4 r0, r1, r2, r3;
            r0.x = fmaxf(acc[ii][0][0].x + btv.x, 0.f);
            r0.y = fmaxf(acc[ii][0][1].x + btv.y, 0.f);
            r0.z = fmaxf(acc[ii][0][2].x + btv.z, 0.f);
            r0.w = fmaxf(acc[ii][0][3].x + btv.w, 0.f);
            r1.x = fmaxf(acc[ii][0][0].y + btv.x, 0.f);
            r1.y = fmaxf(acc[ii][0][1].y + btv.y, 0.f);
            r1.z = fmaxf(acc[ii][0][2].y + btv.z, 0.f);
            r1.w = fmaxf(acc[ii][0][3].y + btv.w, 0.f);
            r2.x = fmaxf(acc[ii][1][0].x + btv.x, 0.f);
            r2.y = fmaxf(acc[ii][1][1].x + btv.y, 0.f);
            r2.z = fmaxf(acc[ii][1][2].x + btv.z, 0.f);
            r2.w = fmaxf(acc[ii][1][3].x + btv.w, 0.f);
            r3.x = fmaxf(acc[ii][1][0].y + btv.x, 0.f);
            r3.y = fmaxf(acc[ii][1][1].y + btv.y, 0.f);
            r3.z = fmaxf(acc[ii][1][2].y + btv.z, 0.f);
            r3.w = fmaxf(acc[ii][1][3].y + btv.w, 0.f);
            *(float4*)(orow + 0)  = r0;
            *(float4*)(orow + 4)  = r1;
            *(float4*)(orow + 8)  = r2;
            *(float4*)(orow + 12) = r3;
        }
    }
}

// ---------------- K4: softmax over j + post-softmax mask -------------------
__global__ __launch_bounds__(256) void k_soft(float* __restrict__ attn,
                                              const int* __restrict__ mask) {
    const int wv = threadIdx.x >> 6, lane = threadIdx.x & 63;
    const int bi = blockIdx.x * 4 + wv;
    const int b = bi >> 9;
    float4* row = (float4*)(attn + (size_t)bi * (NT * NH));

    float4 v[8];
#pragma unroll
    for (int q = 0; q < 8; ++q) v[q] = row[lane + 64 * q];

    float mx[4];
#pragma unroll
    for (int h = 0; h < 4; ++h) {
        float m = ((const float*)&v[0])[h];
#pragma unroll
        for (int q = 1; q < 8; ++q) m = fmaxf(m, ((const float*)&v[q])[h]);
        mx[h] = m;
    }
#pragma unroll
    for (int off = 32; off; off >>= 1) {
#pragma unroll
        for (int h = 0; h < 4; ++h) mx[h] = fmaxf(mx[h], __shfl_xor(mx[h], off));
    }

    float sm[4] = {0.f, 0.f, 0.f, 0.f};
#pragma unroll
    for (int q = 0; q < 8; ++q) {
        float4 e;
        e.x = expf(v[q].x - mx[0]); e.y = expf(v[q].y - mx[1]);
        e.z = expf(v[q].z - mx[2]); e.w = expf(v[q].w - mx[3]);
        v[q] = e;
        sm[0] += e.x; sm[1] += e.y; sm[2] += e.z; sm[3] += e.w;
    }
#pragma unroll
    for (int off = 32; off; off >>= 1) {
#pragma unroll
        for (int h = 0; h < 4; ++h) sm[h] += __shfl_xor(sm[h], off);
    }
    float rinv[4];
#pragma unroll
    for (int h = 0; h < 4; ++h) rinv[h] = 1.0f / sm[h];

    const int mi = mask[bi];
#pragma unroll
    for (int q = 0; q < 8; ++q) {
        const int mj = mask[b * NT + lane + 64 * q];
        const bool z = (mi & mj);
        float4 o;
        o.x = z ? 0.f : v[q].x * rinv[0];
        o.y = z ? 0.f : v[q].y * rinv[1];
        o.z = z ? 0.f : v[q].z * rinv[2];
        o.w = z ? 0.f : v[q].w * rinv[3];
        row[lane + 64 * q] = o;
    }
}

extern "C" void kernel_launch(void* const* d_in, const int* in_sizes, int n_in,
                              void* d_out, int out_size, void* d_ws, size_t ws_size,
                              hipStream_t stream) {
    const float* x      = (const float*)d_in[0];
    const float* W_subj = (const float*)d_in[1];
    const float* b_subj = (const float*)d_in[2];
    const float* W_obj  = (const float*)d_in[3];
    const float* b_obj  = (const float*)d_in[4];
    const float* W_t    = (const float*)d_in[5];
    const float* b_t    = (const float*)d_in[6];
    const unsigned char* mask_raw = (const unsigned char*)d_in[7];

    float* xnew = (float*)d_out;                           // NB*NT*NC2 fp32
    float* attn = xnew + (size_t)NB * NT * NC2;            // NB*NT*NT*NH fp32

    int* wmask          = (int*)d_ws;                                  // 8 KB
    float* subj         = (float*)((char*)d_ws + 8192);                // 2 MB
    float* obj          = subj + (size_t)NB * NT * NC;                 // 2 MB
    unsigned short* xb  = (unsigned short*)(obj + (size_t)NB * NT * NC);  // 2 MB
    unsigned short* wbt = xb + (size_t)NB * NT * NC2;                  // 0.5 MB

    hipLaunchKernelGGL(k_mask, dim3(1), dim3(256), 0, stream, mask_raw, wmask);
    hipLaunchKernelGGL(k_pool, dim3(NB * NT), dim3(NC), 0, stream, x, xnew, xb);
    hipLaunchKernelGGL(k_wcast, dim3(256), dim3(256), 0, stream, W_subj, W_obj, wbt);
    hipLaunchKernelGGL(k_gemm, dim3(256), dim3(256), 0, stream,
                       xb, wbt, b_subj, b_obj, subj, obj);
    hipLaunchKernelGGL(k_rep, dim3(NB * 16 * 16), dim3(256), 0, stream,
                       subj, obj, W_t, b_t, attn);
    hipLaunchKernelGGL(k_soft, dim3(NB * NT / 4), dim3(256), 0, stream, attn, wmask);
}